// Round 4
// baseline (148.940 us; speedup 1.0000x reference)
//
#include <hip/hip_runtime.h>
#include <hip/hip_bf16.h>

#define BATCH 2
#define CH 256
#define NH 4
#define HD 64
#define NGROUP 8
#define CPG 32
#define NTOK 4096
#define EPSV 1e-5f
// scale = hd^-0.5 = 0.125, folded with log2(e) so P = exp2(q'.k)
#define QSCALE 0.1803368801111204f
#define NSPLIT 4

typedef __attribute__((ext_vector_type(8))) short short8;
typedef __attribute__((ext_vector_type(4))) short s4bf;
typedef __attribute__((ext_vector_type(4))) float float4v;
typedef __attribute__((ext_vector_type(2))) float float2v;

__device__ __forceinline__ unsigned short f2bf(float f) {
    union { float f; unsigned u; } v; v.f = f;
    unsigned r = v.u + 0x7FFF + ((v.u >> 16) & 1);
    return (unsigned short)(r >> 16);
}
__device__ __forceinline__ unsigned short f2bf_fast(float f) {
    union { float f; unsigned u; } v; v.f = f;
    return (unsigned short)((v.u + 0x8000u) >> 16);
}
__device__ __forceinline__ float bf2f(unsigned short u) {
    union { unsigned u; float f; } v; v.u = ((unsigned)u) << 16;
    return v.f;
}
// pack two f32 -> one VGPR holding two bf16
__device__ __forceinline__ unsigned pk2bf(float a, float b) {
#if __has_builtin(__builtin_amdgcn_cvt_pk_bf16_f32)
    typedef __attribute__((ext_vector_type(2))) __bf16 bf2v;
    bf2v p = __builtin_amdgcn_cvt_pk_bf16_f32(a, b);
    union { bf2v v; unsigned u; } c; c.v = p;
    return c.u;
#else
    return (unsigned)f2bf_fast(a) | ((unsigned)f2bf_fast(b) << 16);
#endif
}

// async global->LDS DMA, 16B per lane; dst must be wave-uniform (HW adds lane*16)
#define GL2LDS(g, l) __builtin_amdgcn_global_load_lds( \
    (const __attribute__((address_space(1))) void*)(g), \
    (__attribute__((address_space(3))) void*)(l), 16, 0, 0)

// ---------------- prep: fused wcvt + gn_partial (independent work) ----------------
__global__ void prep(const float* __restrict__ x,
                     const float* __restrict__ qkv_w, const float* __restrict__ qkv_b,
                     const float* __restrict__ proj_w,
                     float* __restrict__ psum, float* __restrict__ psq,
                     unsigned short* __restrict__ wq, float* __restrict__ bq,
                     unsigned short* __restrict__ wp) {
    int bx = blockIdx.x;
    int t = threadIdx.x;
    if (bx < 256) {
        // -------- gn_partial --------
        int s = bx & 15, g = (bx >> 4) & 7, b = bx >> 7;
        const float* base = x + ((size_t)(b * CH + g * CPG)) * NTOK + (size_t)s * 8192;
        float sum = 0.f, sq = 0.f;
        const float4v* p4 = (const float4v*)base;
        for (int i = 0; i < 8; ++i) {
            float4v v = p4[t + i * 256];
            for (int j = 0; j < 4; ++j) { sum += v[j]; sq += v[j] * v[j]; }
        }
        for (int off = 32; off; off >>= 1) {
            sum += __shfl_down(sum, off, 64);
            sq  += __shfl_down(sq,  off, 64);
        }
        __shared__ float ls[8];
        int wave = t >> 6, lane = t & 63;
        if (lane == 0) { ls[wave * 2] = sum; ls[wave * 2 + 1] = sq; }
        __syncthreads();
        if (t == 0) {
            float S = 0.f, Q = 0.f;
            for (int w = 0; w < 4; ++w) { S += ls[w * 2]; Q += ls[w * 2 + 1]; }
            int idx = (b * NGROUP + g) * 16 + s;
            psum[idx] = S; psq[idx] = Q;
        }
    } else {
        // -------- wcvt --------
        int idx = (bx - 256) * 256 + t;
        int stride = 256 * 256;
        for (int i = idx; i < 3 * CH * CH; i += stride) {
            float f = qkv_w[i];
            if (i < CH * CH) f *= QSCALE;
            wq[i] = f2bf(f);
        }
        for (int i = idx; i < CH * CH; i += stride) wp[i] = f2bf(proj_w[i]);
        for (int i = idx; i < 3 * CH; i += stride) {
            float f = qkv_b[i];
            if (i < CH) f *= QSCALE;
            bq[i] = f;
        }
    }
}

// ---------------- GroupNorm: normalize + transpose (stats folded in) ----------------
__global__ void gn_norm(const float* __restrict__ x, const float* __restrict__ nw,
                        const float* __restrict__ nb_, const float* __restrict__ psum,
                        const float* __restrict__ psq, unsigned short* __restrict__ hT) {
    int t = threadIdx.x;
    int n = blockIdx.x * 64 + (t & 63);
    int g = blockIdx.y;                    // block covers exactly one group (32 ch)
    int cb = g * 32 + (t >> 6) * 8;
    int b = blockIdx.z;
    float S = 0.f, Q = 0.f;
    for (int s = 0; s < 16; ++s) {
        S += psum[(b * NGROUP + g) * 16 + s];
        Q += psq[(b * NGROUP + g) * 16 + s];
    }
    const float M = (float)(CPG * NTOK);
    float mean = S / M;
    float inv  = rsqrtf(Q / M - mean * mean + EPSV);
    short8 h8;
    for (int j = 0; j < 8; ++j) {
        int c = cb + j;
        float w  = nw[c] * inv;
        float bb = nb_[c] - mean * w;
        float v = x[((size_t)(b * CH + c)) * NTOK + n];
        h8[j] = (short)f2bf(v * w + bb);
    }
    *(short8*)(hT + ((size_t)b * NTOK + n) * CH + cb) = h8;
}

// ---------------- QKV GEMM (bf16 MFMA, LDS-staged B), scatter to qT/kT/v ----------------
__global__ __launch_bounds__(256) void qkv_gemm(const unsigned short* __restrict__ hT,
        const unsigned short* __restrict__ wq, const float* __restrict__ bq,
        unsigned short* __restrict__ qT, unsigned short* __restrict__ kT,
        unsigned short* __restrict__ vv) {
    int nb = blockIdx.x;       // 0..63 (n tile of 64)
    int ob = blockIdx.y;       // 0..11 (o tile of 64)
    int b  = blockIdx.z;
    int t = threadIdx.x;
    int wave = t >> 6, lane = t & 63;
    int l15 = lane & 15, quad = lane >> 4;
    int o0 = ob * 64 + wave * 16;

    __shared__ __align__(16) unsigned short bt[64 * 264];   // 132 dw stride (==4 mod 32)

    short8 aW[8];
    {
        const unsigned short* wr = wq + (size_t)(o0 + l15) * CH + quad * 8;
        for (int kc = 0; kc < 8; ++kc) aW[kc] = *(const short8*)(wr + kc * 32);
    }
    // stage B tile: 64 n-rows x 256 c
    for (int p = 0; p < 8; ++p) {
        int slot = p * 256 + t;
        int r = slot >> 5, c = slot & 31;
        *(short8*)(bt + r * 264 + c * 8) =
            *(const short8*)(hT + ((size_t)b * NTOK + nb * 64 + r) * CH + c * 8);
    }
    __syncthreads();

    float4v acc[4];
    for (int nt = 0; nt < 4; ++nt) for (int r = 0; r < 4; ++r) acc[nt][r] = 0.f;
    for (int kc = 0; kc < 8; ++kc) {
        for (int nt = 0; nt < 4; ++nt) {
            short8 pb = *(const short8*)(bt + (nt * 16 + l15) * 264 + kc * 32 + quad * 8);
            acc[nt] = __builtin_amdgcn_mfma_f32_16x16x32_bf16(aW[kc], pb, acc[nt], 0, 0, 0);
        }
    }
    // seg is block-uniform: o in [ob*64, ob*64+64)
    int seg = ob >> 2;         // 0=q (pre-scaled), 1=k, 2=v
    for (int nt = 0; nt < 4; ++nt) {
        int n = nb * 64 + nt * 16 + l15;
        if (seg < 2) {
            // q/k layout [b,h,n,hd]: the 4 r-values are 4 consecutive hd channels
            // -> pack into one 8-byte store (was 4x 2-byte scattered stores)
            int ob_ = o0 + quad * 4;
            int cch = ob_ & 255;
            int hh = cch >> 6, ci = cch & 63;
            s4bf pk;
            for (int r = 0; r < 4; ++r)
                pk[r] = (short)f2bf(acc[nt][r] + bq[ob_ + r]);
            unsigned short* dst = (seg == 0) ? qT : kT;
            *(s4bf*)(dst + (((size_t)b * NH + hh) * NTOK + n) * HD + ci) = pk;
        } else {
            for (int r = 0; r < 4; ++r) {
                int o = o0 + quad * 4 + r;
                float val = acc[nt][r] + bq[o];
                int cch = o & 255;
                int hh = cch >> 6, ci = cch & 63;
                vv[(((size_t)b * NH + hh) * HD + ci) * NTOK + n] = f2bf(val);
            }
        }
    }
}

// ---------------- Flash attention: S^T trick (register P->PV), 64-key tiles, split x4 ----
// Round-9: VALU-trim on the round-8 structure (which is issue/VALU-bound:
// VALUBusy 45% > MfmaUtil 36%, LDS pipe only ~15%):
//  (1) V-LDS chunk-permuted layout: 16B chunk (d,k8) at byte
//      l15*16 + (quad&1)*8 + k8*256 + ct*2048  ->  read addr = lane_base +
//      nt*512 + ct*2048, ALL immediate offsets (kills ~2-3 VALU x 16 reads/tile
//      of runtime XOR math). Designed-in 4-way bank conflict on V reads is
//      ~25 cyc/tile on a ~15%-busy LDS pipe (invisible).
//  (2) const-ZERO accumulator hoisted out of the loop (kills 32 v_mov/tile).
//  (3) float2 l-accumulation -> v_pk_add_f32 (24 scalar adds -> 16 packed).
// K path (DMA + XOR swizzle, nt-invariant lane base), barriers, XCD swizzle,
// setprio all unchanged from round-8.
__global__ __launch_bounds__(256, 4) void attn_kernel(const unsigned short* __restrict__ qT,
        const unsigned short* __restrict__ kT, const unsigned short* __restrict__ vv,
        unsigned short* __restrict__ opb, float* __restrict__ lpb) {
    // ---- bijective XCD swizzle: f = flat id; hw assigns XCD = f & 7 (round-robin).
    // group g = h + 4*zb (32 groups share one K/V chunk); give each XCD 4 whole groups.
    int f = blockIdx.x + 32 * blockIdx.y + 128 * blockIdx.z;   // 0..1023
    int xcd = f & 7, j = f >> 3;                                // j: 0..127
    int nb = j >> 2;                                            // 0..31
    int g  = xcd + 8 * (j & 3);                                 // 0..31
    int h  = g & 3;
    int zb = g >> 2;
    int sp = zb & 3, b = zb >> 2;
    int t = threadIdx.x, wave = t >> 6, lane = t & 63;
    int l15 = lane & 15, quad = lane >> 4;
    int n0 = nb * 128 + wave * 32;     // wave owns 2 m-tiles of 16 rows
    int kv0 = sp * (NTOK / NSPLIT);

    unsigned short* opart = opb + (size_t)sp * ((size_t)BATCH * NTOK * CH);
    float* lpart = lpb + (size_t)sp * (BATCH * NH * NTOK);

    const unsigned short* qbh = qT + ((size_t)(b * NH + h)) * NTOK * HD;
    const unsigned short* kbh = kT + ((size_t)(b * NH + h)) * NTOK * HD;
    const unsigned short* vbh = vv + ((size_t)(b * NH + h)) * HD * NTOK;

    // double-buffered tiles (32 KB total)
    __shared__ __align__(16) unsigned short kbuf[2][64 * 64];
    __shared__ __align__(16) unsigned short vbuf[2][64 * 64];

    short8 aQ[2][2];   // B-fragment of QK: B[q-row=l15][hd k=quad*8+j]
    for (int mt = 0; mt < 2; ++mt) {
        aQ[mt][0] = *(const short8*)(qbh + (size_t)(n0 + mt * 16 + l15) * HD + quad * 8);
        aQ[mt][1] = *(const short8*)(qbh + (size_t)(n0 + mt * 16 + l15) * HD + 32 + quad * 8);
    }

    float2v lp2[2] = {{0.f, 0.f}, {0.f, 0.f}};   // packed partial denom (q-row = l15)
    float4v o_acc[2][4];
    for (int mt = 0; mt < 2; ++mt)
        for (int ct = 0; ct < 4; ++ct)
            for (int r = 0; r < 4; ++r) o_acc[mt][ct][r] = 0.f;
    const float4v ZERO = {0.f, 0.f, 0.f, 0.f};   // hoisted QK C-input

    // lane-constant read bases (elements/shorts)
    // K: row l15 within each 16-row group; swizzled chunk (quad^(l15&7)) is
    //    nt-invariant because (nt*16+l15)&7 == l15&7.
    const int krd = l15 * 64 + ((quad ^ (l15 & 7)) << 3);          // + nt*1024 (+32 for hi half)
    // V: byte layout l15*16 + (quad&1)*8 + k8*256 + ct*2048, k8 = 2*nt + (quad>>1)
    const int vrd = l15 * 8 + ((quad & 1) << 2) + ((quad >> 1) << 7);  // + nt*256 + ct*1024

    // ---- issue one 64-key tile's K+V DMA: 4 x global_load_lds per wave (16B/lane)
    // K tile: slot s (16B): row r=s>>3, chunk c=s&7; src chunk = c ^ (r&7)
    // V tile: slot s (16B): ct=s>>7, k8=(s>>4)&7, d-low=s&15; src = vbh[(ct*16+dlow)*NTOK + ms + k8*8]
    #define STAGE_TILE(kb_, vb_, ms_)                                                  \
        do {                                                                           \
            _Pragma("unroll")                                                          \
            for (int i = 0; i < 2; ++i) {                                              \
                int slot = (wave * 2 + i) * 64 + lane;                                 \
                int r = slot >> 3, c = slot & 7;                                       \
                GL2LDS(kbh + (size_t)((ms_) + r) * HD + ((c ^ (r & 7)) << 3),          \
                       (kb_) + (wave * 2 + i) * 512);                                  \
            }                                                                          \
            _Pragma("unroll")                                                          \
            for (int i = 0; i < 2; ++i) {                                              \
                int slot = (wave * 2 + i) * 64 + lane;                                 \
                int ct_ = slot >> 7, k8 = (slot >> 4) & 7, dl = slot & 15;             \
                GL2LDS(vbh + (size_t)(ct_ * 16 + dl) * NTOK + (ms_) + k8 * 8,          \
                       (vb_) + (wave * 2 + i) * 512);                                  \
            }                                                                          \
        } while (0)

    STAGE_TILE(kbuf[0], vbuf[0], kv0);
    int cur = 0;

    for (int ms = kv0; ms < kv0 + NTOK / NSPLIT; ms += 64) {
        // own DMA landed; barrier => all waves' DMA landed AND prev compute done
        asm volatile("s_waitcnt vmcnt(0)" ::: "memory");
        __syncthreads();
        if (ms + 64 < kv0 + NTOK / NSPLIT)
            STAGE_TILE(kbuf[cur ^ 1], vbuf[cur ^ 1], ms + 64);   // in flight under compute
        const unsigned short* kb = kbuf[cur] + krd;
        const unsigned short* vb = vbuf[cur] + vrd;

        float4v s[2][4];
        __builtin_amdgcn_s_setprio(1);
#pragma unroll
        for (int nt = 0; nt < 4; ++nt) {
            short8 ak0 = *(const short8*)(kb + nt * 1024);
            short8 ak1 = *(const short8*)(kb + nt * 1024 + 32);
#pragma unroll
            for (int mt = 0; mt < 2; ++mt) {
                float4v z = __builtin_amdgcn_mfma_f32_16x16x32_bf16(ak0, aQ[mt][0], ZERO, 0, 0, 0);
                z = __builtin_amdgcn_mfma_f32_16x16x32_bf16(ak1, aQ[mt][1], z, 0, 0, 0);
                s[mt][nt] = z;
            }
        }
        __builtin_amdgcn_s_setprio(0);
        s4bf aP[2][4];
#pragma unroll
        for (int mt = 0; mt < 2; ++mt) {
#pragma unroll
            for (int nt = 0; nt < 4; ++nt) {
                float e0 = __builtin_amdgcn_exp2f(s[mt][nt][0]);
                float e1 = __builtin_amdgcn_exp2f(s[mt][nt][1]);
                float e2 = __builtin_amdgcn_exp2f(s[mt][nt][2]);
                float e3 = __builtin_amdgcn_exp2f(s[mt][nt][3]);
                float2v ea = {e0, e1}, eb = {e2, e3};
                lp2[mt] += ea + eb;                      // v_pk_add_f32
                union { s4bf v; unsigned u[2]; } c;
                c.u[0] = pk2bf(e0, e1);
                c.u[1] = pk2bf(e2, e3);
                aP[mt][nt] = c.v;
            }
        }
        __builtin_amdgcn_s_setprio(1);
#pragma unroll
        for (int ct = 0; ct < 4; ++ct) {
#pragma unroll
            for (int nt = 0; nt < 4; ++nt) {
                s4bf bv = *(const s4bf*)(vb + nt * 256 + ct * 1024);
#pragma unroll
                for (int mt = 0; mt < 2; ++mt)
                    o_acc[mt][ct] = __builtin_amdgcn_mfma_f32_16x16x16bf16_1k(aP[mt][nt], bv, o_acc[mt][ct], 0, 0, 0);
            }
        }
        __builtin_amdgcn_s_setprio(0);
        cur ^= 1;
    }
    // reduce denom over the 4 quads (key blocks); q-row = l15
    float l_p[2];
    for (int mt = 0; mt < 2; ++mt) {
        l_p[mt] = lp2[mt][0] + lp2[mt][1];
        l_p[mt] += __shfl_xor(l_p[mt], 16, 64);
        l_p[mt] += __shfl_xor(l_p[mt], 32, 64);
    }
    // store unnormalized partial O (bf16): C-layout col=l15=d, row=quad*4+r=q-row
    for (int mt = 0; mt < 2; ++mt) {
        for (int ct = 0; ct < 4; ++ct) {
            for (int r = 0; r < 4; ++r) {
                int n = n0 + mt * 16 + quad * 4 + r;
                int cg = h * HD + ct * 16 + l15;
                opart[((size_t)b * NTOK + n) * CH + cg] = f2bf(o_acc[mt][ct][r]);
            }
        }
        if (lane < 16)
            lpart[((size_t)(b * NH + h)) * NTOK + n0 + mt * 16 + lane] = l_p[mt];
    }
}

// ---------------- Proj GEMM with fused split-combine + bias + residual ----------------
__global__ __launch_bounds__(256) void proj_gemm(const unsigned short* __restrict__ opb,
        const float* __restrict__ lpb, const unsigned short* __restrict__ wp,
        const float* __restrict__ proj_b, const float* __restrict__ x,
        float* __restrict__ out) {
    int nb = blockIdx.x;   // 0..63
    int cb = blockIdx.y;   // 0..3
    int b  = blockIdx.z;
    int t = threadIdx.x, wave = t >> 6, lane = t & 63;
    int l15 = lane & 15, quad = lane >> 4;
    int c0 = cb * 64 + wave * 16;
    const size_t OP = (size_t)BATCH * NTOK * CH;
    const size_t LP = (size_t)BATCH * NH * NTOK;

    __shared__ __align__(16) unsigned short bt[64 * 264];
    __shared__ float rl[64 * 4];

    short8 aW[8];
    {
        const unsigned short* wr = wp + (size_t)(c0 + l15) * CH + quad * 8;
        for (int kc = 0; kc < 8; ++kc) aW[kc] = *(const short8*)(wr + kc * 32);
    }
    // per-row, per-head reciprocal denominators (normalization must precede channel-sum)
    {
        int r = t >> 2, h = t & 3;
        size_t lidx = ((size_t)(b * NH + h)) * NTOK + nb * 64 + r;
        float ls = (lpb[lidx] + lpb[LP + lidx]) + (lpb[2 * LP + lidx] + lpb[3 * LP + lidx]);
        rl[r * 4 + h] = 1.0f / ls;
    }
    __syncthreads();
    // stage normalized O tile from the 4 split partials
    for (int p = 0; p < 8; ++p) {
        int slot = p * 256 + t;
        int r = slot >> 5, c = slot & 31;
        size_t base = ((size_t)b * NTOK + nb * 64 + r) * CH + c * 8;
        short8 o0 = *(const short8*)(opb + base);
        short8 o1 = *(const short8*)(opb + OP + base);
        short8 o2 = *(const short8*)(opb + 2 * OP + base);
        short8 o3 = *(const short8*)(opb + 3 * OP + base);
        float rinv = rl[r * 4 + (c >> 3)];
        short8 m;
        for (int j = 0; j < 8; ++j) {
            float f = (bf2f((unsigned short)o0[j]) + bf2f((unsigned short)o1[j]))
                    + (bf2f((unsigned short)o2[j]) + bf2f((unsigned short)o3[j]));
            m[j] = (short)f2bf(f * rinv);
        }
        *(short8*)(bt + r * 264 + c * 8) = m;
    }
    __syncthreads();

    float4v acc[4];
    for (int nt = 0; nt < 4; ++nt) for (int r = 0; r < 4; ++r) acc[nt][r] = 0.f;
    for (int kc = 0; kc < 8; ++kc) {
        for (int nt = 0; nt < 4; ++nt) {
            short8 pb = *(const short8*)(bt + (nt * 16 + l15) * 264 + kc * 32 + quad * 8);
            acc[nt] = __builtin_amdgcn_mfma_f32_16x16x32_bf16(aW[kc], pb, acc[nt], 0, 0, 0);
        }
    }
    for (int nt = 0; nt < 4; ++nt) {
        int n = nb * 64 + nt * 16 + l15;
        for (int r = 0; r < 4; ++r) {
            int cc = c0 + quad * 4 + r;
            size_t idx = ((size_t)(b * CH + cc)) * NTOK + n;
            out[idx] = acc[nt][r] + proj_b[cc] + x[idx];
        }
    }
}

extern "C" void kernel_launch(void* const* d_in, const int* in_sizes, int n_in,
                              void* d_out, int out_size, void* d_ws, size_t ws_size,
                              hipStream_t stream) {
    const float* x      = (const float*)d_in[0];
    const float* norm_w = (const float*)d_in[1];
    const float* norm_b = (const float*)d_in[2];
    const float* qkv_w  = (const float*)d_in[3];
    const float* qkv_b  = (const float*)d_in[4];
    const float* proj_w = (const float*)d_in[5];
    const float* proj_b = (const float*)d_in[6];
    float* out = (float*)d_out;

    char* ws = (char*)d_ws;
    float* psum  = (float*)ws;                       // 256 f
    float* psq   = (float*)(ws + 1024);              // 256 f
    float* bqs   = (float*)(ws + 4096);              // 768 f
    unsigned short* wqb = (unsigned short*)(ws + 8192);        // 3*256*256 bf16 -> 401408
    unsigned short* wpb = (unsigned short*)(ws + 401408);      // 256*256 bf16   -> 532480
    float* lpb = (float*)(ws + 532480);              // 4 * 2*4*4096 f = 512 KB
    const size_t MB4 = 4194304;
    unsigned short* hT  = (unsigned short*)(ws + 2097152);     // 4 MB (aliases op slot 0)
    unsigned short* opb = hT;                                  // 4 x 4 MB partials
    unsigned short* qT = (unsigned short*)(ws + 2097152 + 4 * MB4);
    unsigned short* kT = (unsigned short*)(ws + 2097152 + 5 * MB4);
    unsigned short* vv = (unsigned short*)(ws + 2097152 + 6 * MB4);

    prep<<<dim3(512), dim3(256), 0, stream>>>(x, qkv_w, qkv_b, proj_w, psum, psq, wqb, bqs, wpb);
    gn_norm<<<dim3(64, 8, BATCH), dim3(256), 0, stream>>>(x, norm_w, norm_b, psum, psq, hT);
    qkv_gemm<<<dim3(64, 12, BATCH), dim3(256), 0, stream>>>(hT, wqb, bqs, qT, kT, vv);
    attn_kernel<<<dim3(32, NH, BATCH * NSPLIT), dim3(256), 0, stream>>>(qT, kT, vv, opb, lpb);
    proj_gemm<<<dim3(64, 4, BATCH), dim3(256), 0, stream>>>(opb, lpb, wpb, proj_b, x, out);
}

// Round 5
// 146.877 us; speedup vs baseline: 1.0140x; 1.0140x over previous
//
#include <hip/hip_runtime.h>
#include <hip/hip_bf16.h>

#define BATCH 2
#define CH 256
#define NH 4
#define HD 64
#define NGROUP 8
#define CPG 32
#define NTOK 4096
#define EPSV 1e-5f
// scale = hd^-0.5 = 0.125, folded with log2(e) so P = exp2(q'.k)
#define QSCALE 0.1803368801111204f
#define NSPLIT 4

typedef __attribute__((ext_vector_type(8))) short short8;
typedef __attribute__((ext_vector_type(4))) short s4bf;
typedef __attribute__((ext_vector_type(4))) float float4v;

__device__ __forceinline__ unsigned short f2bf(float f) {
    union { float f; unsigned u; } v; v.f = f;
    unsigned r = v.u + 0x7FFF + ((v.u >> 16) & 1);
    return (unsigned short)(r >> 16);
}
__device__ __forceinline__ unsigned short f2bf_fast(float f) {
    union { float f; unsigned u; } v; v.f = f;
    return (unsigned short)((v.u + 0x8000u) >> 16);
}
__device__ __forceinline__ float bf2f(unsigned short u) {
    union { unsigned u; float f; } v; v.u = ((unsigned)u) << 16;
    return v.f;
}
// pack two f32 -> one VGPR holding two bf16
__device__ __forceinline__ unsigned pk2bf(float a, float b) {
#if __has_builtin(__builtin_amdgcn_cvt_pk_bf16_f32)
    typedef __attribute__((ext_vector_type(2))) __bf16 bf2v;
    bf2v p = __builtin_amdgcn_cvt_pk_bf16_f32(a, b);
    union { bf2v v; unsigned u; } c; c.v = p;
    return c.u;
#else
    return (unsigned)f2bf_fast(a) | ((unsigned)f2bf_fast(b) << 16);
#endif
}

// async global->LDS DMA, 16B per lane; dst must be wave-uniform (HW adds lane*16)
#define GL2LDS(g, l) __builtin_amdgcn_global_load_lds( \
    (const __attribute__((address_space(1))) void*)(g), \
    (__attribute__((address_space(3))) void*)(l), 16, 0, 0)

// ---------------- prep: fused wcvt + gn_partial (independent work) ----------------
__global__ void prep(const float* __restrict__ x,
                     const float* __restrict__ qkv_w, const float* __restrict__ qkv_b,
                     const float* __restrict__ proj_w,
                     float* __restrict__ psum, float* __restrict__ psq,
                     unsigned short* __restrict__ wq, float* __restrict__ bq,
                     unsigned short* __restrict__ wp) {
    int bx = blockIdx.x;
    int t = threadIdx.x;
    if (bx < 256) {
        // -------- gn_partial --------
        int s = bx & 15, g = (bx >> 4) & 7, b = bx >> 7;
        const float* base = x + ((size_t)(b * CH + g * CPG)) * NTOK + (size_t)s * 8192;
        float sum = 0.f, sq = 0.f;
        const float4v* p4 = (const float4v*)base;
        for (int i = 0; i < 8; ++i) {
            float4v v = p4[t + i * 256];
            for (int j = 0; j < 4; ++j) { sum += v[j]; sq += v[j] * v[j]; }
        }
        for (int off = 32; off; off >>= 1) {
            sum += __shfl_down(sum, off, 64);
            sq  += __shfl_down(sq,  off, 64);
        }
        __shared__ float ls[8];
        int wave = t >> 6, lane = t & 63;
        if (lane == 0) { ls[wave * 2] = sum; ls[wave * 2 + 1] = sq; }
        __syncthreads();
        if (t == 0) {
            float S = 0.f, Q = 0.f;
            for (int w = 0; w < 4; ++w) { S += ls[w * 2]; Q += ls[w * 2 + 1]; }
            int idx = (b * NGROUP + g) * 16 + s;
            psum[idx] = S; psq[idx] = Q;
        }
    } else {
        // -------- wcvt --------
        int idx = (bx - 256) * 256 + t;
        int stride = 256 * 256;
        for (int i = idx; i < 3 * CH * CH; i += stride) {
            float f = qkv_w[i];
            if (i < CH * CH) f *= QSCALE;
            wq[i] = f2bf(f);
        }
        for (int i = idx; i < CH * CH; i += stride) wp[i] = f2bf(proj_w[i]);
        for (int i = idx; i < 3 * CH; i += stride) {
            float f = qkv_b[i];
            if (i < CH) f *= QSCALE;
            bq[i] = f;
        }
    }
}

// ---------------- GroupNorm: normalize + transpose (stats folded in) ----------------
__global__ void gn_norm(const float* __restrict__ x, const float* __restrict__ nw,
                        const float* __restrict__ nb_, const float* __restrict__ psum,
                        const float* __restrict__ psq, unsigned short* __restrict__ hT) {
    int t = threadIdx.x;
    int n = blockIdx.x * 64 + (t & 63);
    int g = blockIdx.y;                    // block covers exactly one group (32 ch)
    int cb = g * 32 + (t >> 6) * 8;
    int b = blockIdx.z;
    float S = 0.f, Q = 0.f;
    for (int s = 0; s < 16; ++s) {
        S += psum[(b * NGROUP + g) * 16 + s];
        Q += psq[(b * NGROUP + g) * 16 + s];
    }
    const float M = (float)(CPG * NTOK);
    float mean = S / M;
    float inv  = rsqrtf(Q / M - mean * mean + EPSV);
    short8 h8;
    for (int j = 0; j < 8; ++j) {
        int c = cb + j;
        float w  = nw[c] * inv;
        float bb = nb_[c] - mean * w;
        float v = x[((size_t)(b * CH + c)) * NTOK + n];
        h8[j] = (short)f2bf(v * w + bb);
    }
    *(short8*)(hT + ((size_t)b * NTOK + n) * CH + cb) = h8;
}

// ---------------- QKV GEMM (bf16 MFMA, LDS-staged B), scatter to qT/kT/v ----------------
// Round-10: XCD-aware remap -- all 12 ob-blocks of one (nb,b) tile land on the same
// XCD, so the shared 32KB hT tile is L2-hit after the first block reads it.
__global__ __launch_bounds__(256) void qkv_gemm(const unsigned short* __restrict__ hT,
        const unsigned short* __restrict__ wq, const float* __restrict__ bq,
        unsigned short* __restrict__ qT, unsigned short* __restrict__ kT,
        unsigned short* __restrict__ vv) {
    // flat id; hw XCD = f & 7. Give each XCD whole (nb,b) groups of 12 ob-blocks.
    int f = blockIdx.x + 64 * blockIdx.y + 768 * blockIdx.z;   // 0..1535
    int xcd = f & 7, j = f >> 3;        // j: 0..191
    int ob = j % 12;                    // 0..11
    int p  = xcd + 8 * (j / 12);        // 0..127
    int nb = p & 63;                    // 0..63
    int b  = p >> 6;                    // 0..1
    int t = threadIdx.x;
    int wave = t >> 6, lane = t & 63;
    int l15 = lane & 15, quad = lane >> 4;
    int o0 = ob * 64 + wave * 16;

    __shared__ __align__(16) unsigned short bt[64 * 264];   // 132 dw stride (==4 mod 32)

    short8 aW[8];
    {
        const unsigned short* wr = wq + (size_t)(o0 + l15) * CH + quad * 8;
        for (int kc = 0; kc < 8; ++kc) aW[kc] = *(const short8*)(wr + kc * 32);
    }
    // stage B tile: 64 n-rows x 256 c
    for (int p2 = 0; p2 < 8; ++p2) {
        int slot = p2 * 256 + t;
        int r = slot >> 5, c = slot & 31;
        *(short8*)(bt + r * 264 + c * 8) =
            *(const short8*)(hT + ((size_t)b * NTOK + nb * 64 + r) * CH + c * 8);
    }
    __syncthreads();

    float4v acc[4];
    for (int nt = 0; nt < 4; ++nt) for (int r = 0; r < 4; ++r) acc[nt][r] = 0.f;
    for (int kc = 0; kc < 8; ++kc) {
        for (int nt = 0; nt < 4; ++nt) {
            short8 pb = *(const short8*)(bt + (nt * 16 + l15) * 264 + kc * 32 + quad * 8);
            acc[nt] = __builtin_amdgcn_mfma_f32_16x16x32_bf16(aW[kc], pb, acc[nt], 0, 0, 0);
        }
    }
    // seg is block-uniform: o in [ob*64, ob*64+64)
    int seg = ob >> 2;         // 0=q (pre-scaled), 1=k, 2=v
    for (int nt = 0; nt < 4; ++nt) {
        int n = nb * 64 + nt * 16 + l15;
        if (seg < 2) {
            // q/k layout [b,h,n,hd]: the 4 r-values are 4 consecutive hd channels
            // -> pack into one 8-byte store
            int ob_ = o0 + quad * 4;
            int cch = ob_ & 255;
            int hh = cch >> 6, ci = cch & 63;
            s4bf pk;
            for (int r = 0; r < 4; ++r)
                pk[r] = (short)f2bf(acc[nt][r] + bq[ob_ + r]);
            unsigned short* dst = (seg == 0) ? qT : kT;
            *(s4bf*)(dst + (((size_t)b * NH + hh) * NTOK + n) * HD + ci) = pk;
        } else {
            for (int r = 0; r < 4; ++r) {
                int o = o0 + quad * 4 + r;
                float val = acc[nt][r] + bq[o];
                int cch = o & 255;
                int hh = cch >> 6, ci = cch & 63;
                vv[(((size_t)b * NH + hh) * HD + ci) * NTOK + n] = f2bf(val);
            }
        }
    }
}

// ---------------- Flash attention: S^T trick (register P->PV), 64-key tiles, split x4 ----
// Round-10: revert to the round-8 (55.9us) verified addressing. Round-9's hoisted
// K hi-half read (krd + 32) was WRONG for lanes with (l15&7)>=4 (the +32 carries
// into the row bits; XOR != add) -- it passed the harness only because softmax
// outputs are convex combos of V. Explicit ((quad+4)^r7)<<3 restored; V staging
// and reads are the round-8 coalesced XOR forms. Only kept micro-opt: hoisted
// const-ZERO C-input for the QK MFMAs (saves the per-tile accumulator zeroing).
__global__ __launch_bounds__(256, 4) void attn_kernel(const unsigned short* __restrict__ qT,
        const unsigned short* __restrict__ kT, const unsigned short* __restrict__ vv,
        unsigned short* __restrict__ opb, float* __restrict__ lpb) {
    // ---- bijective XCD swizzle: f = flat id; hw assigns XCD = f & 7 (round-robin).
    // group g = h + 4*zb (32 groups share one K/V chunk); give each XCD 4 whole groups.
    int f = blockIdx.x + 32 * blockIdx.y + 128 * blockIdx.z;   // 0..1023
    int xcd = f & 7, j = f >> 3;                                // j: 0..127
    int nb = j >> 2;                                            // 0..31
    int g  = xcd + 8 * (j & 3);                                 // 0..31
    int h  = g & 3;
    int zb = g >> 2;
    int sp = zb & 3, b = zb >> 2;
    int t = threadIdx.x, wave = t >> 6, lane = t & 63;
    int l15 = lane & 15, quad = lane >> 4;
    int n0 = nb * 128 + wave * 32;     // wave owns 2 m-tiles of 16 rows
    int kv0 = sp * (NTOK / NSPLIT);

    unsigned short* opart = opb + (size_t)sp * ((size_t)BATCH * NTOK * CH);
    float* lpart = lpb + (size_t)sp * (BATCH * NH * NTOK);

    const unsigned short* qbh = qT + ((size_t)(b * NH + h)) * NTOK * HD;
    const unsigned short* kbh = kT + ((size_t)(b * NH + h)) * NTOK * HD;
    const unsigned short* vbh = vv + ((size_t)(b * NH + h)) * HD * NTOK;

    // double-buffered tiles (32 KB total)
    __shared__ __align__(16) unsigned short kbuf[2][64 * 64];
    __shared__ __align__(16) unsigned short vbuf[2][64 * 64];

    short8 aQ[2][2];   // B-fragment of QK: B[q-row=l15][hd k=quad*8+j]
    for (int mt = 0; mt < 2; ++mt) {
        aQ[mt][0] = *(const short8*)(qbh + (size_t)(n0 + mt * 16 + l15) * HD + quad * 8);
        aQ[mt][1] = *(const short8*)(qbh + (size_t)(n0 + mt * 16 + l15) * HD + 32 + quad * 8);
    }

    float l_p[2] = {0.f, 0.f};         // per-lane partial denom (q-row = l15)
    float4v o_acc[2][4];
    for (int mt = 0; mt < 2; ++mt)
        for (int ct = 0; ct < 4; ++ct)
            for (int r = 0; r < 4; ++r) o_acc[mt][ct][r] = 0.f;
    const float4v ZERO = {0.f, 0.f, 0.f, 0.f};   // hoisted QK C-input

    // ---- issue one 64-key tile's K+V DMA: 4 x global_load_lds per wave (16B/lane)
    // K tile [key r][d]: 128B rows, 8 chunks; src chunk = c ^ (r&7)
    // V tile [d r][key]: 128B rows, 8 chunks; src chunk = c ^ (r&7)
    #define STAGE_TILE(kb_, vb_, ms_)                                                  \
        do {                                                                           \
            _Pragma("unroll")                                                          \
            for (int i = 0; i < 2; ++i) {                                              \
                int slot = (wave * 2 + i) * 64 + lane;                                 \
                int r = slot >> 3, c = slot & 7;                                       \
                GL2LDS(kbh + (size_t)((ms_) + r) * HD + ((c ^ (r & 7)) << 3),          \
                       (kb_) + (wave * 2 + i) * 512);                                  \
            }                                                                          \
            _Pragma("unroll")                                                          \
            for (int i = 0; i < 2; ++i) {                                              \
                int slot = (wave * 2 + i) * 64 + lane;                                 \
                int r = slot >> 3, c = slot & 7;                                       \
                GL2LDS(vbh + (size_t)r * NTOK + (ms_) + ((c ^ (r & 7)) << 3),          \
                       (vb_) + (wave * 2 + i) * 512);                                  \
            }                                                                          \
        } while (0)

    STAGE_TILE(kbuf[0], vbuf[0], kv0);
    int cur = 0;

    for (int ms = kv0; ms < kv0 + NTOK / NSPLIT; ms += 64) {
        // own DMA landed; barrier => all waves' DMA landed AND prev compute done
        asm volatile("s_waitcnt vmcnt(0)" ::: "memory");
        __syncthreads();
        if (ms + 64 < kv0 + NTOK / NSPLIT)
            STAGE_TILE(kbuf[cur ^ 1], vbuf[cur ^ 1], ms + 64);   // in flight under compute
        const unsigned short* kb = kbuf[cur];
        const unsigned short* vb = vbuf[cur];

        float4v s[2][4];
        __builtin_amdgcn_s_setprio(1);
#pragma unroll
        for (int nt = 0; nt < 4; ++nt) {
            int krow = nt * 16 + l15;
            int r7 = krow & 7;
            short8 ak0 = *(const short8*)(kb + krow * 64 + ((quad ^ r7) << 3));
            short8 ak1 = *(const short8*)(kb + krow * 64 + (((quad + 4) ^ r7) << 3));
#pragma unroll
            for (int mt = 0; mt < 2; ++mt) {
                float4v z = __builtin_amdgcn_mfma_f32_16x16x32_bf16(ak0, aQ[mt][0], ZERO, 0, 0, 0);
                z = __builtin_amdgcn_mfma_f32_16x16x32_bf16(ak1, aQ[mt][1], z, 0, 0, 0);
                s[mt][nt] = z;
            }
        }
        __builtin_amdgcn_s_setprio(0);
        s4bf aP[2][4];
#pragma unroll
        for (int mt = 0; mt < 2; ++mt) {
#pragma unroll
            for (int nt = 0; nt < 4; ++nt) {
                float e0 = __builtin_amdgcn_exp2f(s[mt][nt][0]);
                float e1 = __builtin_amdgcn_exp2f(s[mt][nt][1]);
                float e2 = __builtin_amdgcn_exp2f(s[mt][nt][2]);
                float e3 = __builtin_amdgcn_exp2f(s[mt][nt][3]);
                l_p[mt] += (e0 + e1) + (e2 + e3);
                union { s4bf v; unsigned u[2]; } c;
                c.u[0] = pk2bf(e0, e1);
                c.u[1] = pk2bf(e2, e3);
                aP[mt][nt] = c.v;
            }
        }
        __builtin_amdgcn_s_setprio(1);
#pragma unroll
        for (int ct = 0; ct < 4; ++ct) {
#pragma unroll
            for (int nt = 0; nt < 4; ++nt) {
                int vr = ct * 16 + l15;
                int c8 = nt * 2 + (quad >> 1);
                s4bf bv = *(const s4bf*)(vb + vr * 64 +
                                         ((c8 ^ (vr & 7)) << 3) + ((quad & 1) << 2));
#pragma unroll
                for (int mt = 0; mt < 2; ++mt)
                    o_acc[mt][ct] = __builtin_amdgcn_mfma_f32_16x16x16bf16_1k(aP[mt][nt], bv, o_acc[mt][ct], 0, 0, 0);
            }
        }
        __builtin_amdgcn_s_setprio(0);
        cur ^= 1;
    }
    // reduce denom over the 4 quads (key blocks); q-row = l15
    for (int mt = 0; mt < 2; ++mt) {
        l_p[mt] += __shfl_xor(l_p[mt], 16, 64);
        l_p[mt] += __shfl_xor(l_p[mt], 32, 64);
    }
    // store unnormalized partial O (bf16): C-layout col=l15=d, row=quad*4+r=q-row
    for (int mt = 0; mt < 2; ++mt) {
        for (int ct = 0; ct < 4; ++ct) {
            for (int r = 0; r < 4; ++r) {
                int n = n0 + mt * 16 + quad * 4 + r;
                int cg = h * HD + ct * 16 + l15;
                opart[((size_t)b * NTOK + n) * CH + cg] = f2bf(o_acc[mt][ct][r]);
            }
        }
        if (lane < 16)
            lpart[((size_t)(b * NH + h)) * NTOK + n0 + mt * 16 + lane] = l_p[mt];
    }
}

// ---------------- Proj GEMM with fused split-combine + bias + residual ----------------
// Round-10: XCD-aware remap -- all 4 cb-blocks of one (nb,b) tile land on the same
// XCD, so the shared 128KB opb panel is L2-hit after the first block reads it.
__global__ __launch_bounds__(256) void proj_gemm(const unsigned short* __restrict__ opb,
        const float* __restrict__ lpb, const unsigned short* __restrict__ wp,
        const float* __restrict__ proj_b, const float* __restrict__ x,
        float* __restrict__ out) {
    int f = blockIdx.x + 64 * blockIdx.y + 256 * blockIdx.z;   // 0..511
    int xcd = f & 7, j = f >> 3;    // j: 0..63
    int cb = j & 3;                 // 0..3
    int p  = xcd + 8 * (j >> 2);    // 0..127
    int nb = p & 63;                // 0..63
    int b  = p >> 6;                // 0..1
    int t = threadIdx.x, wave = t >> 6, lane = t & 63;
    int l15 = lane & 15, quad = lane >> 4;
    int c0 = cb * 64 + wave * 16;
    const size_t OP = (size_t)BATCH * NTOK * CH;
    const size_t LP = (size_t)BATCH * NH * NTOK;

    __shared__ __align__(16) unsigned short bt[64 * 264];
    __shared__ float rl[64 * 4];

    short8 aW[8];
    {
        const unsigned short* wr = wp + (size_t)(c0 + l15) * CH + quad * 8;
        for (int kc = 0; kc < 8; ++kc) aW[kc] = *(const short8*)(wr + kc * 32);
    }
    // per-row, per-head reciprocal denominators (normalization must precede channel-sum)
    {
        int r = t >> 2, h = t & 3;
        size_t lidx = ((size_t)(b * NH + h)) * NTOK + nb * 64 + r;
        float ls = (lpb[lidx] + lpb[LP + lidx]) + (lpb[2 * LP + lidx] + lpb[3 * LP + lidx]);
        rl[r * 4 + h] = 1.0f / ls;
    }
    __syncthreads();
    // stage normalized O tile from the 4 split partials
    for (int p2 = 0; p2 < 8; ++p2) {
        int slot = p2 * 256 + t;
        int r = slot >> 5, c = slot & 31;
        size_t base = ((size_t)b * NTOK + nb * 64 + r) * CH + c * 8;
        short8 o0 = *(const short8*)(opb + base);
        short8 o1 = *(const short8*)(opb + OP + base);
        short8 o2 = *(const short8*)(opb + 2 * OP + base);
        short8 o3 = *(const short8*)(opb + 3 * OP + base);
        float rinv = rl[r * 4 + (c >> 3)];
        short8 m;
        for (int jj = 0; jj < 8; ++jj) {
            float ff = (bf2f((unsigned short)o0[jj]) + bf2f((unsigned short)o1[jj]))
                     + (bf2f((unsigned short)o2[jj]) + bf2f((unsigned short)o3[jj]));
            m[jj] = (short)f2bf(ff * rinv);
        }
        *(short8*)(bt + r * 264 + c * 8) = m;
    }
    __syncthreads();

    float4v acc[4];
    for (int nt = 0; nt < 4; ++nt) for (int r = 0; r < 4; ++r) acc[nt][r] = 0.f;
    for (int kc = 0; kc < 8; ++kc) {
        for (int nt = 0; nt < 4; ++nt) {
            short8 pb = *(const short8*)(bt + (nt * 16 + l15) * 264 + kc * 32 + quad * 8);
            acc[nt] = __builtin_amdgcn_mfma_f32_16x16x32_bf16(aW[kc], pb, acc[nt], 0, 0, 0);
        }
    }
    for (int nt = 0; nt < 4; ++nt) {
        int n = nb * 64 + nt * 16 + l15;
        for (int r = 0; r < 4; ++r) {
            int cc = c0 + quad * 4 + r;
            size_t idx = ((size_t)(b * CH + cc)) * NTOK + n;
            out[idx] = acc[nt][r] + proj_b[cc] + x[idx];
        }
    }
}

extern "C" void kernel_launch(void* const* d_in, const int* in_sizes, int n_in,
                              void* d_out, int out_size, void* d_ws, size_t ws_size,
                              hipStream_t stream) {
    const float* x      = (const float*)d_in[0];
    const float* norm_w = (const float*)d_in[1];
    const float* norm_b = (const float*)d_in[2];
    const float* qkv_w  = (const float*)d_in[3];
    const float* qkv_b  = (const float*)d_in[4];
    const float* proj_w = (const float*)d_in[5];
    const float* proj_b = (const float*)d_in[6];
    float* out = (float*)d_out;

    char* ws = (char*)d_ws;
    float* psum  = (float*)ws;                       // 256 f
    float* psq   = (float*)(ws + 1024);              // 256 f
    float* bqs   = (float*)(ws + 4096);              // 768 f
    unsigned short* wqb = (unsigned short*)(ws + 8192);        // 3*256*256 bf16 -> 401408
    unsigned short* wpb = (unsigned short*)(ws + 401408);      // 256*256 bf16   -> 532480
    float* lpb = (float*)(ws + 532480);              // 4 * 2*4*4096 f = 512 KB
    const size_t MB4 = 4194304;
    unsigned short* hT  = (unsigned short*)(ws + 2097152);     // 4 MB (aliases op slot 0)
    unsigned short* opb = hT;                                  // 4 x 4 MB partials
    unsigned short* qT = (unsigned short*)(ws + 2097152 + 4 * MB4);
    unsigned short* kT = (unsigned short*)(ws + 2097152 + 5 * MB4);
    unsigned short* vv = (unsigned short*)(ws + 2097152 + 6 * MB4);

    prep<<<dim3(512), dim3(256), 0, stream>>>(x, qkv_w, qkv_b, proj_w, psum, psq, wqb, bqs, wpb);
    gn_norm<<<dim3(64, 8, BATCH), dim3(256), 0, stream>>>(x, norm_w, norm_b, psum, psq, hT);
    qkv_gemm<<<dim3(64, 12, BATCH), dim3(256), 0, stream>>>(hT, wqb, bqs, qT, kT, vv);
    attn_kernel<<<dim3(32, NH, BATCH * NSPLIT), dim3(256), 0, stream>>>(qT, kT, vv, opb, lpb);
    proj_gemm<<<dim3(64, 4, BATCH), dim3(256), 0, stream>>>(opb, lpb, wpb, proj_b, x, out);
}